// Round 1
// baseline (501.319 us; speedup 1.0000x reference)
//
#include <hip/hip_runtime.h>
#include <math.h>

#define D64   64
#define STR   68      // padded LDS row stride (floats): breaks power-of-2 bank conflicts
#define NVEC  2016
#define NT    256
#define MORD  8       // Taylor order
#define THETA 0.5f

// C = (A @ B) * cscale + addI * I, 64x64, one block of 256 threads.
// Each thread computes a 4x4 tile. All operands in LDS with row stride STR.
__device__ __forceinline__ void matmul64(const float* __restrict__ Am,
                                         const float* __restrict__ Bm,
                                         float* __restrict__ Cm,
                                         float cscale, float addI, int tid)
{
    const int r0 = (tid >> 4) << 2;   // 0,4,...,60
    const int c0 = (tid & 15) << 2;   // 0,4,...,60
    float acc[4][4];
#pragma unroll
    for (int i = 0; i < 4; ++i)
#pragma unroll
        for (int j = 0; j < 4; ++j) acc[i][j] = 0.f;

#pragma unroll 4
    for (int k = 0; k < 64; k += 4) {
        float aa[4][4], bb[4][4];
#pragma unroll
        for (int kk = 0; kk < 4; ++kk) {
            float4 t = *(const float4*)&Bm[(k + kk) * STR + c0];
            bb[kk][0] = t.x; bb[kk][1] = t.y; bb[kk][2] = t.z; bb[kk][3] = t.w;
        }
#pragma unroll
        for (int i = 0; i < 4; ++i) {
            float4 t = *(const float4*)&Am[(r0 + i) * STR + k];
            aa[i][0] = t.x; aa[i][1] = t.y; aa[i][2] = t.z; aa[i][3] = t.w;
        }
#pragma unroll
        for (int i = 0; i < 4; ++i)
#pragma unroll
            for (int j = 0; j < 4; ++j)
                acc[i][j] += aa[i][0] * bb[0][j] + aa[i][1] * bb[1][j]
                           + aa[i][2] * bb[2][j] + aa[i][3] * bb[3][j];
    }

#pragma unroll
    for (int i = 0; i < 4; ++i) {
        float4 o;
        o.x = acc[i][0] * cscale + ((r0 + i) == (c0 + 0) ? addI : 0.f);
        o.y = acc[i][1] * cscale + ((r0 + i) == (c0 + 1) ? addI : 0.f);
        o.z = acc[i][2] * cscale + ((r0 + i) == (c0 + 2) ? addI : 0.f);
        o.w = acc[i][3] * cscale + ((r0 + i) == (c0 + 3) ? addI : 0.f);
        *(float4*)&Cm[(r0 + i) * STR + c0] = o;
    }
}

__global__ void __launch_bounds__(NT)
SkewSymMatrixExp_kernel(const float* __restrict__ vin, float* __restrict__ out)
{
    __shared__ float A[D64 * STR];
    __shared__ float B0[D64 * STR];
    __shared__ float B1[D64 * STR];
    __shared__ float cs[NT];
    __shared__ float s_norm;

    const int tid = threadIdx.x;
    const float* v = vin + (size_t)blockIdx.x * NVEC;

    // ---- build skew-symmetric A from packed strict-upper vector ----
    for (int i = tid; i < D64 * STR; i += NT) A[i] = 0.f;
    __syncthreads();

    for (int p = tid; p < NVEC; p += NT) {
        // row i of strict-upper triu, row-major: offset(i) = 63*i - i*(i-1)/2
        int i = (int)((127.0f - sqrtf(16129.0f - 8.0f * (float)p)) * 0.5f);
        if (i < 0) i = 0;
        if (i > 62) i = 62;
        while (i > 0 && (63 * i - ((i * (i - 1)) >> 1)) > p) --i;
        while (i < 62 && (63 * (i + 1) - (((i + 1) * i) >> 1)) <= p) ++i;
        const int off = 63 * i - ((i * (i - 1)) >> 1);
        const int j = i + 1 + (p - off);
        const float val = v[p];
        A[i * STR + j] = -val;   // upper = -v
        A[j * STR + i] =  val;   // lower = +v
    }
    __syncthreads();

    // ---- 1-norm (max abs column sum) for scaling ----
    {
        const int col = tid & 63, rq = tid >> 6;
        float part = 0.f;
        for (int r = rq * 16; r < rq * 16 + 16; ++r) part += fabsf(A[r * STR + col]);
        cs[tid] = part;
    }
    __syncthreads();
    if (tid < 64) {
        float t = cs[tid] + cs[tid + 64] + cs[tid + 128] + cs[tid + 192];
        for (int o = 32; o > 0; o >>= 1) t = fmaxf(t, __shfl_down(t, o, 64));
        if (tid == 0) s_norm = t;
    }
    __syncthreads();

    int k = 0;
    {
        const float nrm = s_norm;
        if (nrm > THETA) k = (int)ceilf(log2f(nrm / THETA));
        if (k < 0) k = 0;
        if (k > 15) k = 15;
    }
    const float scale = exp2f((float)(-k));

    for (int i = tid; i < D64 * STR; i += NT) A[i] *= scale;

    // ---- X = I + A/MORD  (first Horner step, no matmul needed) ----
    for (int i = tid; i < D64 * D64; i += NT) {
        const int r = i >> 6, c = i & 63;
        B0[r * STR + c] = A[r * STR + c] * (1.0f / (float)MORD) + ((r == c) ? 1.f : 0.f);
    }
    __syncthreads();

    float* X = B0;
    float* T = B1;

    // ---- Horner: X = I + (A @ X)/j, j = MORD-1 .. 1 ----
#pragma unroll 1
    for (int j = MORD - 1; j >= 1; --j) {
        matmul64(A, X, T, 1.0f / (float)j, 1.0f, tid);
        __syncthreads();
        float* tmp = X; X = T; T = tmp;
    }

    // ---- k squarings: X = X @ X ----
#pragma unroll 1
    for (int s = 0; s < k; ++s) {
        matmul64(X, X, T, 1.0f, 0.0f, tid);
        __syncthreads();
        float* tmp = X; X = T; T = tmp;
    }

    // ---- write result (dense 64x64, row-major) ----
    float* po = out + (size_t)blockIdx.x * (D64 * D64);
    for (int i = tid; i < 1024; i += NT) {
        const int r = i >> 4, c4 = (i & 15) << 2;
        *(float4*)&po[r * 64 + c4] = *(const float4*)&X[r * STR + c4];
    }
}

extern "C" void kernel_launch(void* const* d_in, const int* in_sizes, int n_in,
                              void* d_out, int out_size, void* d_ws, size_t ws_size,
                              hipStream_t stream) {
    const float* vin = (const float*)d_in[0];
    float* out = (float*)d_out;
    const int batch = in_sizes[0] / NVEC;   // 4096
    hipLaunchKernelGGL(SkewSymMatrixExp_kernel, dim3(batch), dim3(NT), 0, stream,
                       vin, out);
}

// Round 2
// 220.731 us; speedup vs baseline: 2.2712x; 2.2712x over previous
//
#include <hip/hip_runtime.h>
#include <math.h>

#define NVEC  2016
#define NT    256
#define STRU  68          // u32 row stride (272 B = 17*16: b128-aligned rows, 2-way max bank alias)
#define KEXP  7           // fixed squaring count; scale = 2^-7
#define NMAT  4096

typedef __attribute__((ext_vector_type(8))) short short8;
typedef __attribute__((ext_vector_type(4))) float v4f;

#define MFMA(a, b, c) __builtin_amdgcn_mfma_f32_16x16x32_bf16((a), (b), (c), 0, 0, 0)

// pack fp32 -> (bf16_hi << 16) | bf16_lo, both RNE-rounded
static __device__ __forceinline__ unsigned pack_hl(float x) {
    unsigned u  = __float_as_uint(x);
    unsigned hu = (u + 0x7FFFu + ((u >> 16) & 1u)) & 0xFFFF0000u;   // rne bf16 of x, as f32 bits
    float    r  = x - __uint_as_float(hu);                           // exact residual
    unsigned ru = __float_as_uint(r);
    unsigned rr = ru + 0x7FFFu + ((ru >> 16) & 1u);                  // rne bf16 of r (take hi16)
    // bytes: [rr.b2, rr.b3, hu.b2, hu.b3]  ->  (hi<<16)|lo
    return __builtin_amdgcn_perm(hu, rr, 0x07060302u);
}

struct FragHL { short8 h, l; };

// load 8 consecutive packed u32 (k-contiguous) -> hi/lo bf16 fragments
static __device__ __forceinline__ FragHL load_frag(const unsigned* p) {
    uint4 U0 = *(const uint4*)(p);
    uint4 U1 = *(const uint4*)(p + 4);
    union { unsigned u[4]; short8 s; } H, L;
    H.u[0] = __builtin_amdgcn_perm(U0.y, U0.x, 0x07060302u);
    H.u[1] = __builtin_amdgcn_perm(U0.w, U0.z, 0x07060302u);
    H.u[2] = __builtin_amdgcn_perm(U1.y, U1.x, 0x07060302u);
    H.u[3] = __builtin_amdgcn_perm(U1.w, U1.z, 0x07060302u);
    L.u[0] = __builtin_amdgcn_perm(U0.y, U0.x, 0x05040100u);
    L.u[1] = __builtin_amdgcn_perm(U0.w, U0.z, 0x05040100u);
    L.u[2] = __builtin_amdgcn_perm(U1.y, U1.x, 0x05040100u);
    L.u[3] = __builtin_amdgcn_perm(U1.w, U1.z, 0x05040100u);
    FragHL f; f.h = H.s; f.l = L.s; return f;
}

// A-operand fragments (row-major source): rows Rw..Rw+31, all k
static __device__ __forceinline__ void load_afrag(FragHL Af[2][2], const unsigned* Arow,
                                                  int q, int m, int Rw) {
#pragma unroll
    for (int i = 0; i < 2; ++i)
#pragma unroll
        for (int c = 0; c < 2; ++c)
            Af[i][c] = load_frag(&Arow[(unsigned)(Rw + 16 * i + m) * STRU + 32 * c + 8 * q]);
}

// acc(32x32 quadrant) = A @ B ; B read col-major from Bcol (cols Cw..Cw+31)
static __device__ __forceinline__ void mm_core(const FragHL Af[2][2], const unsigned* Bcol,
                                               v4f acc[2][2], int q, int m, int Cw) {
#pragma unroll
    for (int i = 0; i < 2; ++i)
#pragma unroll
        for (int j = 0; j < 2; ++j) acc[i][j] = (v4f){0.f, 0.f, 0.f, 0.f};
#pragma unroll
    for (int j = 0; j < 2; ++j) {
#pragma unroll
        for (int c = 0; c < 2; ++c) {
            FragHL B = load_frag(&Bcol[(unsigned)(Cw + 16 * j + m) * STRU + 32 * c + 8 * q]);
#pragma unroll
            for (int i = 0; i < 2; ++i) {
                acc[i][j] = MFMA(Af[i][c].h, B.h, acc[i][j]);
                acc[i][j] = MFMA(Af[i][c].h, B.l, acc[i][j]);
                acc[i][j] = MFMA(Af[i][c].l, B.h, acc[i][j]);
                acc[i][j] = MFMA(Af[i][c].l, B.l, acc[i][j]);
            }
        }
    }
}

// X = acc*cs + addI*I, stored packed to Xc (col-major) and optionally Xr (row-major)
static __device__ __forceinline__ void epi_lds(const v4f acc[2][2], unsigned* Xr, unsigned* Xc,
                                               float cs, float addI, bool writeRow,
                                               int q, int m, int Rw, int Cw) {
#pragma unroll
    for (int i = 0; i < 2; ++i) {
        const int row0 = Rw + 16 * i + 4 * q;
#pragma unroll
        for (int j = 0; j < 2; ++j) {
            const int col = Cw + 16 * j + m;
            unsigned pk[4];
#pragma unroll
            for (int r = 0; r < 4; ++r) {
                float x = acc[i][j][r] * cs + ((row0 + r) == col ? addI : 0.f);
                pk[r] = pack_hl(x);
                if (writeRow) Xr[(unsigned)(row0 + r) * STRU + col] = pk[r];
            }
            *(uint4*)&Xc[(unsigned)col * STRU + row0] = make_uint4(pk[0], pk[1], pk[2], pk[3]);
        }
    }
}

static __device__ __forceinline__ void epi_glob(const v4f acc[2][2], float* outp,
                                                int q, int m, int Rw, int Cw) {
#pragma unroll
    for (int i = 0; i < 2; ++i) {
        const int row0 = Rw + 16 * i + 4 * q;
#pragma unroll
        for (int j = 0; j < 2; ++j) {
            const int col = Cw + 16 * j + m;
#pragma unroll
            for (int r = 0; r < 4; ++r)
                outp[(unsigned)(row0 + r) * 64 + col] = acc[i][j][r];
        }
    }
}

__global__ void __launch_bounds__(NT, 3)
SkewSymMatrixExp_kernel(const float* __restrict__ vin, float* __restrict__ out)
{
    __shared__ __attribute__((aligned(16))) unsigned Apk[64 * STRU];
    __shared__ __attribute__((aligned(16))) unsigned Xr[64 * STRU];
    __shared__ __attribute__((aligned(16))) unsigned Xc[64 * STRU];

    const int tid  = threadIdx.x;
    const int wave = tid >> 6;
    const int lane = tid & 63;
    const int q    = lane >> 4;     // MFMA quad
    const int m    = lane & 15;     // MFMA row/col within tile
    const int Rw   = (wave >> 1) * 32;   // wave's output row band
    const int Cw   = (wave & 1) * 32;    // wave's output col band
    const float* v = vin + (size_t)blockIdx.x * NVEC;

    // ---- zero packed A ----
    for (int i = tid; i < 64 * STRU; i += NT) Apk[i] = 0u;
    __syncthreads();

    // ---- scatter packed skew-symmetric A, pre-scaled by 2^-7 ----
    for (int p = tid; p < NVEC; p += NT) {
        int i = (int)((127.0f - sqrtf(16129.0f - 8.0f * (float)p)) * 0.5f);
        if (i < 0) i = 0;
        if (i > 62) i = 62;
        while (i > 0 && (63 * i - ((i * (i - 1)) >> 1)) > p) --i;
        while (i < 62 && (63 * (i + 1) - (((i + 1) * i) >> 1)) <= p) ++i;
        const int off = 63 * i - ((i * (i - 1)) >> 1);
        const int j = i + 1 + (p - off);
        const float val = v[p] * 0.0078125f;       // exact /128
        const unsigned pk = pack_hl(val);
        Apk[(unsigned)j * STRU + i] = pk;                 // lower: +val
        Apk[(unsigned)i * STRU + j] = pk ^ 0x80008000u;   // upper: -val (flip both signs)
    }
    __syncthreads();

    // ---- cache A fragments in registers (reused across all 7 Horner matmuls) ----
    FragHL Af[2][2];
    load_afrag(Af, Apk, q, m, Rw);

    // ---- X0 = I + A/8  -> Xc (col-major) only; uses A[row][col] = -A[col][row] for coalescing ----
    for (int idx = tid; idx < 4096; idx += NT) {
        const int col = idx >> 6, row = idx & 63;
        const unsigned u = Apk[(unsigned)col * STRU + row];               // = A[col][row]
        const float a = __uint_as_float(u & 0xFFFF0000u) + __uint_as_float(u << 16);
        const float x = -a * 0.125f + ((row == col) ? 1.f : 0.f);        // A[row][col]/8 + I
        Xc[(unsigned)col * STRU + row] = pack_hl(x);
    }
    __syncthreads();

    v4f acc[2][2];

    // ---- Horner: X = (A @ X)/jj + I, jj = 7..1 (A from registers, X from Xc) ----
#pragma unroll 1
    for (int jj = 7; jj >= 1; --jj) {
        mm_core(Af, Xc, acc, q, m, Cw);
        __syncthreads();                                   // all reads of Xc complete
        // only the final Horner result needs the row-major copy (for squaring A-operand)
        epi_lds(acc, Xr, Xc, 1.0f / (float)jj, 1.f, (jj == 1), q, m, Rw, Cw);
        __syncthreads();                                   // writes visible
    }

    // ---- 7 squarings: X = X @ X (last one streams f32 straight to global) ----
#pragma unroll 1
    for (int s = 0; s < KEXP; ++s) {
        FragHL Xf[2][2];
        load_afrag(Xf, Xr, q, m, Rw);
        mm_core(Xf, Xc, acc, q, m, Cw);
        __syncthreads();
        if (s < KEXP - 1) {
            epi_lds(acc, Xr, Xc, 1.f, 0.f, true, q, m, Rw, Cw);
            __syncthreads();
        } else {
            epi_glob(acc, out + (size_t)blockIdx.x * 4096, q, m, Rw, Cw);
        }
    }
}

extern "C" void kernel_launch(void* const* d_in, const int* in_sizes, int n_in,
                              void* d_out, int out_size, void* d_ws, size_t ws_size,
                              hipStream_t stream) {
    const float* vin = (const float*)d_in[0];
    float* out = (float*)d_out;
    const int batch = in_sizes[0] / NVEC;   // 4096
    hipLaunchKernelGGL(SkewSymMatrixExp_kernel, dim3(batch), dim3(NT), 0, stream,
                       vin, out);
}

// Round 3
// 197.343 us; speedup vs baseline: 2.5403x; 1.1185x over previous
//
#include <hip/hip_runtime.h>
#include <math.h>

#define NVEC  2016
#define NT    512
#define STRP  72     // bf16 plane row stride (elements): 144 B rows, 16B-aligned, 4-bank row shift
#define STRU  68     // packed-u32 row stride: 272 B rows, 16B-aligned
#define KEXP  7      // squarings; scale = 2^-7

typedef __attribute__((ext_vector_type(8))) short short8;
typedef __attribute__((ext_vector_type(4))) float v4f;

#define MFMA(a, b, c) __builtin_amdgcn_mfma_f32_16x16x32_bf16((a), (b), (c), 0, 0, 0)

// RNE-round f32 bits to bf16 (result in top 16 bits)
static __device__ __forceinline__ unsigned rne_hi(unsigned ru) {
    return ru + 0x7FFFu + ((ru >> 16) & 1u);
}

// fp32 -> (trunc_bf16(x) << 16) | rne_bf16(x - trunc(x)).  Pair error ~2^-24 rel.
// Negation = ^0x80008000 (trunc is sign-magnitude, RNE symmetric).
static __device__ __forceinline__ unsigned pack_hl(float x) {
    unsigned u = __float_as_uint(x);
    float r = x - __uint_as_float(u & 0xFFFF0000u);          // exact residual
    unsigned l = rne_hi(__float_as_uint(r));
    return __builtin_amdgcn_perm(u, l, 0x07060302u);         // [u.hi16 | l.hi16]
}

struct FragHL { short8 h, l; };

// 8 packed u32 (k-contiguous) -> hi/lo bf16 fragments (8 perms)
static __device__ __forceinline__ FragHL load_frag_packed(const unsigned* p) {
    uint4 U0 = *(const uint4*)(p);
    uint4 U1 = *(const uint4*)(p + 4);
    union { unsigned u[4]; short8 s; } H, L;
    H.u[0] = __builtin_amdgcn_perm(U0.y, U0.x, 0x07060302u);
    H.u[1] = __builtin_amdgcn_perm(U0.w, U0.z, 0x07060302u);
    H.u[2] = __builtin_amdgcn_perm(U1.y, U1.x, 0x07060302u);
    H.u[3] = __builtin_amdgcn_perm(U1.w, U1.z, 0x07060302u);
    L.u[0] = __builtin_amdgcn_perm(U0.y, U0.x, 0x05040100u);
    L.u[1] = __builtin_amdgcn_perm(U0.w, U0.z, 0x05040100u);
    L.u[2] = __builtin_amdgcn_perm(U1.y, U1.x, 0x05040100u);
    L.u[3] = __builtin_amdgcn_perm(U1.w, U1.z, 0x05040100u);
    FragHL f; f.h = H.s; f.l = L.s; return f;
}

__global__ void __launch_bounds__(NT, 6)
SkewSymMatrixExp_kernel(const float* __restrict__ vin, float* __restrict__ out)
{
    // U: A packed u32 (row-major), later X row-major packed (A dead after reg-cache + X0 init)
    __shared__ __attribute__((aligned(16))) unsigned U[64 * STRU];     // 17408 B
    // X col-major bf16 planes (B-operand side): perm-free b128 fragment loads
    __shared__ __attribute__((aligned(16))) short Xh[64 * STRP];       // 9216 B
    __shared__ __attribute__((aligned(16))) short Xl[64 * STRP];       // 9216 B
    // total 35840 B -> LDS allows 4 blocks/CU; launch_bounds targets 24 waves/CU

    const int tid  = threadIdx.x;
    const int wave = tid >> 6;
    const int lane = tid & 63;
    const int q    = lane >> 4;          // MFMA quad
    const int m    = lane & 15;          // MFMA row/col within 16-tile
    const int Rw   = (wave >> 2) * 32;   // wave's 32-row band
    const int Cw16 = (wave & 3) * 16;    // wave's 16-col band
    const int col  = Cw16 + m;           // this lane's output column
    const float* v = vin + (size_t)blockIdx.x * NVEC;

    // ---- zero packed A ----
    for (int i = tid; i < 64 * STRU; i += NT) U[i] = 0u;
    __syncthreads();

    // ---- scatter packed skew-symmetric A, pre-scaled by 2^-7 ----
    for (int p = tid; p < NVEC; p += NT) {
        int i = (int)((127.0f - sqrtf(16129.0f - 8.0f * (float)p)) * 0.5f);
        if (i < 0) i = 0;
        if (i > 62) i = 62;
        while (i > 0 && (63 * i - ((i * (i - 1)) >> 1)) > p) --i;
        while (i < 62 && (63 * (i + 1) - (((i + 1) * i) >> 1)) <= p) ++i;
        const int off = 63 * i - ((i * (i - 1)) >> 1);
        const int j = i + 1 + (p - off);
        const unsigned pk = pack_hl(v[p] * 0.0078125f);
        U[(unsigned)j * STRU + i] = pk;                 // lower: +val
        U[(unsigned)i * STRU + j] = pk ^ 0x80008000u;   // upper: -val
    }
    __syncthreads();

    // ---- cache A fragments in registers (A-operand for all 7 Horner mults) ----
    FragHL Af[2][2];
#pragma unroll
    for (int i = 0; i < 2; ++i)
#pragma unroll
        for (int c = 0; c < 2; ++c)
            Af[i][c] = load_frag_packed(&U[(unsigned)(Rw + 16 * i + m) * STRU + 32 * c + 8 * q]);

    // ---- X0 = I + A/8 -> col-major planes (read A rows = X0 cols via skew symmetry) ----
    for (int u0 = tid; u0 < 1024; u0 += NT) {
        const int c0 = u0 & 63, rq = u0 >> 6;            // col, row-quad
        uint4 aq = *(const uint4*)&U[(unsigned)c0 * STRU + 4 * rq];
        unsigned ub[4], lb[4];
        const unsigned* ap = &aq.x;
#pragma unroll
        for (int r = 0; r < 4; ++r) {
            const unsigned a = ap[r];
            const float av = __uint_as_float(a & 0xFFFF0000u) + __uint_as_float(a << 16);
            const float x = -0.125f * av + ((4 * rq + r) == c0 ? 1.f : 0.f);   // I + A[r][c]/8
            const unsigned u = __float_as_uint(x);
            ub[r] = u;
            lb[r] = rne_hi(__float_as_uint(x - __uint_as_float(u & 0xFFFF0000u)));
        }
        uint2 hp, lp;
        hp.x = __builtin_amdgcn_perm(ub[1], ub[0], 0x07060302u);
        hp.y = __builtin_amdgcn_perm(ub[3], ub[2], 0x07060302u);
        lp.x = __builtin_amdgcn_perm(lb[1], lb[0], 0x07060302u);
        lp.y = __builtin_amdgcn_perm(lb[3], lb[2], 0x07060302u);
        *(uint2*)&Xh[(unsigned)c0 * STRP + 4 * rq] = hp;
        *(uint2*)&Xl[(unsigned)c0 * STRP + 4 * rq] = lp;
    }
    __syncthreads();

    v4f acc[2];

    // ---- Horner: X = (A @ X)/jj + I, jj = 7..1 ----
#pragma unroll 1
    for (int jj = 7; jj >= 1; --jj) {
        // prefetch B fragments (perm-free), then barrier: reads done before anyone writes
        short8 bh[2], bl[2];
#pragma unroll
        for (int c = 0; c < 2; ++c) {
            bh[c] = *(const short8*)&Xh[(unsigned)col * STRP + 32 * c + 8 * q];
            bl[c] = *(const short8*)&Xl[(unsigned)col * STRP + 32 * c + 8 * q];
        }
        __syncthreads();

#pragma unroll
        for (int i = 0; i < 2; ++i) acc[i] = (v4f){0.f, 0.f, 0.f, 0.f};
#pragma unroll
        for (int c = 0; c < 2; ++c)
#pragma unroll
            for (int i = 0; i < 2; ++i) {
                acc[i] = MFMA(Af[i][c].h, bh[c], acc[i]);
                acc[i] = MFMA(Af[i][c].l, bh[c], acc[i]);
                acc[i] = MFMA(Af[i][c].h, bl[c], acc[i]);
            }

        const float cs = 1.0f / (float)jj;
        const bool wU = (jj == 1);                       // only final Horner needs row-major copy
#pragma unroll
        for (int i = 0; i < 2; ++i) {
            const int row0 = Rw + 16 * i + 4 * q;
            unsigned ub[4], lb[4];
#pragma unroll
            for (int r = 0; r < 4; ++r) {
                const float x = acc[i][r] * cs + ((row0 + r) == col ? 1.f : 0.f);
                const unsigned u = __float_as_uint(x);
                ub[r] = u;
                lb[r] = rne_hi(__float_as_uint(x - __uint_as_float(u & 0xFFFF0000u)));
            }
            uint2 hp, lp;
            hp.x = __builtin_amdgcn_perm(ub[1], ub[0], 0x07060302u);
            hp.y = __builtin_amdgcn_perm(ub[3], ub[2], 0x07060302u);
            lp.x = __builtin_amdgcn_perm(lb[1], lb[0], 0x07060302u);
            lp.y = __builtin_amdgcn_perm(lb[3], lb[2], 0x07060302u);
            *(uint2*)&Xh[(unsigned)col * STRP + row0] = hp;
            *(uint2*)&Xl[(unsigned)col * STRP + row0] = lp;
            if (wU) {
#pragma unroll
                for (int r = 0; r < 4; ++r)
                    U[(unsigned)(row0 + r) * STRU + col] =
                        __builtin_amdgcn_perm(ub[r], lb[r], 0x07060302u);
            }
        }
        __syncthreads();
    }

    // ---- 7 squarings: X = X @ X ----
#pragma unroll 1
    for (int s = 0; s < KEXP; ++s) {
        // A-operand fragments from row-major packed U (unpack: 32 perms)
#pragma unroll
        for (int i = 0; i < 2; ++i)
#pragma unroll
            for (int c = 0; c < 2; ++c)
                Af[i][c] = load_frag_packed(&U[(unsigned)(Rw + 16 * i + m) * STRU + 32 * c + 8 * q]);
        short8 bh[2], bl[2];
#pragma unroll
        for (int c = 0; c < 2; ++c) {
            bh[c] = *(const short8*)&Xh[(unsigned)col * STRP + 32 * c + 8 * q];
            bl[c] = *(const short8*)&Xl[(unsigned)col * STRP + 32 * c + 8 * q];
        }
        __syncthreads();

#pragma unroll
        for (int i = 0; i < 2; ++i) acc[i] = (v4f){0.f, 0.f, 0.f, 0.f};
#pragma unroll
        for (int c = 0; c < 2; ++c)
#pragma unroll
            for (int i = 0; i < 2; ++i) {
                acc[i] = MFMA(Af[i][c].h, bh[c], acc[i]);
                acc[i] = MFMA(Af[i][c].l, bh[c], acc[i]);
                acc[i] = MFMA(Af[i][c].h, bl[c], acc[i]);
            }

        if (s < KEXP - 1) {
#pragma unroll
            for (int i = 0; i < 2; ++i) {
                const int row0 = Rw + 16 * i + 4 * q;
                unsigned ub[4], lb[4];
#pragma unroll
                for (int r = 0; r < 4; ++r) {
                    const unsigned u = __float_as_uint(acc[i][r]);
                    ub[r] = u;
                    lb[r] = rne_hi(__float_as_uint(acc[i][r] - __uint_as_float(u & 0xFFFF0000u)));
                }
                uint2 hp, lp;
                hp.x = __builtin_amdgcn_perm(ub[1], ub[0], 0x07060302u);
                hp.y = __builtin_amdgcn_perm(ub[3], ub[2], 0x07060302u);
                lp.x = __builtin_amdgcn_perm(lb[1], lb[0], 0x07060302u);
                lp.y = __builtin_amdgcn_perm(lb[3], lb[2], 0x07060302u);
                *(uint2*)&Xh[(unsigned)col * STRP + row0] = hp;
                *(uint2*)&Xl[(unsigned)col * STRP + row0] = lp;
#pragma unroll
                for (int r = 0; r < 4; ++r)
                    U[(unsigned)(row0 + r) * STRU + col] =
                        __builtin_amdgcn_perm(ub[r], lb[r], 0x07060302u);
            }
            __syncthreads();
        } else {
            float* po = out + (size_t)blockIdx.x * 4096;
#pragma unroll
            for (int i = 0; i < 2; ++i) {
                const int row0 = Rw + 16 * i + 4 * q;
#pragma unroll
                for (int r = 0; r < 4; ++r)
                    po[(unsigned)(row0 + r) * 64 + col] = acc[i][r];
            }
        }
    }
}

extern "C" void kernel_launch(void* const* d_in, const int* in_sizes, int n_in,
                              void* d_out, int out_size, void* d_ws, size_t ws_size,
                              hipStream_t stream) {
    const float* vin = (const float*)d_in[0];
    float* out = (float*)d_out;
    const int batch = in_sizes[0] / NVEC;   // 4096
    hipLaunchKernelGGL(SkewSymMatrixExp_kernel, dim3(batch), dim3(NT), 0, stream,
                       vin, out);
}

// Round 4
// 192.846 us; speedup vs baseline: 2.5996x; 1.0233x over previous
//
#include <hip/hip_runtime.h>
#include <math.h>

#define NVEC 2016
#define NT   512
#define STRP 72     // shorts per plane row: 144 B, 16B-aligned, breaks pow2 banks

typedef __attribute__((ext_vector_type(8))) short short8;
typedef __attribute__((ext_vector_type(4))) float v4f;

#define MFMA(a,b,c) __builtin_amdgcn_mfma_f32_16x16x32_bf16((a),(b),(c),0,0,0)

// RNE f32->bf16, result in low 16 bits
static __device__ __forceinline__ unsigned rne16(unsigned u){ return (u + 0x7FFFu + ((u>>16)&1u)) >> 16; }

// x -> h = trunc-bf16 (top16), l = rne-bf16 of exact residual. pair rel err ~2^-16.
static __device__ __forceinline__ void split_hl(float x, unsigned &h, unsigned &l){
    unsigned u = __float_as_uint(x);
    h = u >> 16;
    float r = x - __uint_as_float(u & 0xFFFF0000u);
    l = rne16(__float_as_uint(r));
}

static __device__ __forceinline__ short8 ldp(const unsigned short* P, int row, int off){
    return *(const short8*)&P[row*STRP + off];
}

static __device__ __forceinline__ short8 neg8(short8 a){
    union { unsigned u[4]; short8 s; } X; X.s = a;
    X.u[0]^=0x80008000u; X.u[1]^=0x80008000u; X.u[2]^=0x80008000u; X.u[3]^=0x80008000u;
    return X.s;
}

// bf16 h-frag of (ca*A2 + cb*A4), read k-contig from col planes (symmetric operands)
static __device__ __forceinline__ short8 poly_frag(const unsigned short* P2, const unsigned short* P4,
                                                   int col, int off, float ca, float cb){
    short8 a2 = ldp(P2, col, off);
    short8 a4 = ldp(P4, col, off);
    union { unsigned short u[8]; short8 s; } R;
#pragma unroll
    for (int e=0;e<8;++e){
        float fa = __uint_as_float(((unsigned)(unsigned short)a2[e])<<16);
        float fb = __uint_as_float(((unsigned)(unsigned short)a4[e])<<16);
        R.u[e] = (unsigned short)rne16(__float_as_uint(ca*fa + cb*fb));
    }
    return R.s;
}

// read 4 consecutive rows of column `col` as f32 pairs (h+l planes)
static __device__ __forceinline__ void pair4(const unsigned short* Ph, const unsigned short* Pl,
                                             int col, int row0, float o[4]){
    uint2 h = *(const uint2*)&Ph[col*STRP+row0];
    uint2 l = *(const uint2*)&Pl[col*STRP+row0];
    o[0] = __uint_as_float(h.x<<16)           + __uint_as_float(l.x<<16);
    o[1] = __uint_as_float(h.x & 0xFFFF0000u) + __uint_as_float(l.x & 0xFFFF0000u);
    o[2] = __uint_as_float(h.y<<16)           + __uint_as_float(l.y<<16);
    o[3] = __uint_as_float(h.y & 0xFFFF0000u) + __uint_as_float(l.y & 0xFFFF0000u);
}

// write 4 rows of column `col` to col planes (vector), optionally row planes (scatter)
static __device__ __forceinline__ void wr_planes(unsigned short* Ch, unsigned short* Cl,
                                                 unsigned short* Rh, unsigned short* Rl,
                                                 int col, int row0, const float x[4], bool wrow){
    unsigned h[4], l[4];
#pragma unroll
    for (int r=0;r<4;++r) split_hl(x[r], h[r], l[r]);
    uint2 hp, lp;
    hp.x = h[0] | (h[1]<<16); hp.y = h[2] | (h[3]<<16);
    lp.x = l[0] | (l[1]<<16); lp.y = l[2] | (l[3]<<16);
    *(uint2*)&Ch[col*STRP+row0] = hp;
    *(uint2*)&Cl[col*STRP+row0] = lp;
    if (wrow){
#pragma unroll
        for (int r=0;r<4;++r){
            Rh[(row0+r)*STRP+col] = (unsigned short)h[r];
            Rl[(row0+r)*STRP+col] = (unsigned short)l[r];
        }
    }
}

__global__ void __launch_bounds__(NT, 4)
SkewSymMatrixExp_kernel(const float* __restrict__ vin, float* __restrict__ out)
{
    // 6 planes x 9216 B = 55296 B (+tmp) -> 2 blocks/CU
    __shared__ __attribute__((aligned(16))) unsigned short PAh[64*STRP], PAl[64*STRP]; // A col -> V col
    __shared__ __attribute__((aligned(16))) unsigned short P2h[64*STRP], P2l[64*STRP]; // A2 col -> X row
    __shared__ __attribute__((aligned(16))) unsigned short P4h[64*STRP], P4l[64*STRP]; // A4 col -> X col
    __shared__ float tmp[NT];
    __shared__ int s_kk;

    unsigned short* Vh = PAh; unsigned short* Vl = PAl;
    unsigned short* Xrh = P2h; unsigned short* Xrl = P2l;
    unsigned short* Xch = P4h; unsigned short* Xcl = P4l;

    const int tid  = threadIdx.x;
    const int wave = tid >> 6;
    const int lane = tid & 63;
    const int q    = lane >> 4;
    const int m    = lane & 15;
    const int Rw   = (wave >> 2) * 32;
    const int col  = (wave & 3) * 16 + m;
    const float* v = vin + (size_t)blockIdx.x * NVEC;

    // ---- zero A col planes ----
    for (int i = tid; i < 64*STRP/2; i += NT){ ((unsigned*)PAh)[i] = 0u; ((unsigned*)PAl)[i] = 0u; }
    __syncthreads();

    // ---- scatter A (UNSCALED) into col planes: P[c*S+r] = A[r][c] ----
    for (int p = tid; p < NVEC; p += NT) {
        int i = (int)((127.0f - sqrtf(16129.0f - 8.0f * (float)p)) * 0.5f);
        if (i < 0) i = 0;
        if (i > 62) i = 62;
        while (i > 0 && (63*i - ((i*(i-1))>>1)) > p) --i;
        while (i < 62 && (63*(i+1) - (((i+1)*i)>>1)) <= p) ++i;
        const int off = 63*i - ((i*(i-1))>>1);
        const int j = i + 1 + (p - off);
        unsigned h, l; split_hl(v[p], h, l);
        // A[i][j] = -val -> plane[j*S+i] ; A[j][i] = +val -> plane[i*S+j]
        PAh[j*STRP+i] = (unsigned short)(h ^ 0x8000u);
        PAl[j*STRP+i] = (unsigned short)(l ^ 0x8000u);
        PAh[i*STRP+j] = (unsigned short)h;
        PAl[i*STRP+j] = (unsigned short)l;
    }
    __syncthreads();

    // ---- R1: A2 = A*A (unscaled). A-frags into registers (kept for final round). ----
    short8 Ah[2][2], Al[2][2];
#pragma unroll
    for (int i=0;i<2;++i)
#pragma unroll
        for (int c=0;c<2;++c){
            Ah[i][c] = neg8(ldp(PAh, Rw+16*i+m, 32*c+8*q));   // A[row][k] = -Acol[row*S+k]
            Al[i][c] = neg8(ldp(PAl, Rw+16*i+m, 32*c+8*q));
        }
    {
        short8 bh[2], bl[2];
#pragma unroll
        for (int c=0;c<2;++c){ bh[c]=ldp(PAh,col,32*c+8*q); bl[c]=ldp(PAl,col,32*c+8*q); }
        v4f acc[2];
#pragma unroll
        for (int i=0;i<2;++i) acc[i] = (v4f){0.f,0.f,0.f,0.f};
#pragma unroll
        for (int c=0;c<2;++c)
#pragma unroll
            for (int i=0;i<2;++i){
                acc[i] = MFMA(Ah[i][c], bh[c], acc[i]);
                acc[i] = MFMA(Al[i][c], bh[c], acc[i]);
                acc[i] = MFMA(Ah[i][c], bl[c], acc[i]);
            }
        // A2 symmetric: col planes only, unscaled
#pragma unroll
        for (int i=0;i<2;++i){
            float x[4] = {acc[i][0], acc[i][1], acc[i][2], acc[i][3]};
            wr_planes(P2h, P2l, 0, 0, col, Rw+16*i+4*q, x, false);
        }
    }
    __syncthreads();

    // ---- pick k from ||A2||_1 : spectral(A) <= sqrt(||A2||_1); target theta<=1.6 ----
    {
        int c0 = tid & 63, seg = tid >> 6;
        uint4 w = *(const uint4*)&P2h[c0*STRP + seg*8];
        unsigned ws[4] = {w.x, w.y, w.z, w.w};
        float s = 0.f;
#pragma unroll
        for (int e=0;e<4;++e){
            s += __uint_as_float((ws[e] & 0x7FFFu) << 16);
            s += __uint_as_float(ws[e] & 0x7FFF0000u);
        }
        tmp[tid] = s;
    }
    __syncthreads();
    if (tid < 64){
        float s = 0.f;
#pragma unroll
        for (int w=0;w<8;++w) s += tmp[w*64 + tid];
#pragma unroll
        for (int o=32;o>0;o>>=1) s = fmaxf(s, __shfl_down(s, o, 64));
        if (tid == 0){
            float est = sqrtf(s) * 0.625f;          // sqrt(n1)/1.6
            int k = 0;
            if (est > 1.f) k = (int)ceilf(log2f(est));
            if (k > 8) k = 8;
            s_kk = k;
        }
    }
    __syncthreads();
    const int   kq = s_kk;
    const float s1 = exp2f(-(float)kq);             // B = s1*A
    const float s2 = s1*s1;                          // B^2 = s2*A2
    const float s4 = s2*s2;

    v4f acc[2];

    // ---- R2: A4 = (s2*A2)^2 = s4 * A2*A2 (A2 sym: col planes both sides) ----
    {
        short8 ah2[2][2], al2[2][2], bh[2], bl[2];
#pragma unroll
        for (int i=0;i<2;++i)
#pragma unroll
            for (int c=0;c<2;++c){
                ah2[i][c] = ldp(P2h, Rw+16*i+m, 32*c+8*q);
                al2[i][c] = ldp(P2l, Rw+16*i+m, 32*c+8*q);
            }
#pragma unroll
        for (int c=0;c<2;++c){ bh[c]=ldp(P2h,col,32*c+8*q); bl[c]=ldp(P2l,col,32*c+8*q); }
#pragma unroll
        for (int i=0;i<2;++i) acc[i] = (v4f){0.f,0.f,0.f,0.f};
#pragma unroll
        for (int c=0;c<2;++c)
#pragma unroll
            for (int i=0;i<2;++i){
                acc[i] = MFMA(ah2[i][c], bh[c], acc[i]);
                acc[i] = MFMA(al2[i][c], bh[c], acc[i]);
                acc[i] = MFMA(ah2[i][c], bl[c], acc[i]);
            }
#pragma unroll
        for (int i=0;i<2;++i){
            float x[4] = {s4*acc[i][0], s4*acc[i][1], s4*acc[i][2], s4*acc[i][3]};
            wr_planes(P4h, P4l, 0, 0, col, Rw+16*i+4*q, x, false);   // A4 sym, scaled
        }
    }
    __syncthreads();

    // ---- R3: V = s1*( I + B2/6 + B4/120 + A4*(B2/5040 + B4/362880) ) -> col planes ----
    {
        short8 a4f[2][2], vhi[2];
#pragma unroll
        for (int i=0;i<2;++i)
#pragma unroll
            for (int c=0;c<2;++c) a4f[i][c] = ldp(P4h, Rw+16*i+m, 32*c+8*q);  // A4 sym, h-only
#pragma unroll
        for (int c=0;c<2;++c)
            vhi[c] = poly_frag(P2h, P4h, col, 32*c+8*q, s2/5040.f, 1.f/362880.f);
#pragma unroll
        for (int i=0;i<2;++i) acc[i] = (v4f){0.f,0.f,0.f,0.f};
#pragma unroll
        for (int c=0;c<2;++c)
#pragma unroll
            for (int i=0;i<2;++i) acc[i] = MFMA(a4f[i][c], vhi[c], acc[i]);
#pragma unroll
        for (int i=0;i<2;++i){
            const int row0 = Rw+16*i+4*q;
            float e2[4], e4[4], x[4];
            pair4(P2h, P2l, col, row0, e2);
            pair4(P4h, P4l, col, row0, e4);
#pragma unroll
            for (int r=0;r<4;++r)
                x[r] = s1*( acc[i][r] + e2[r]*(s2/6.f) + e4[r]*(1.f/120.f)
                            + ((row0+r)==col ? 1.f : 0.f) );
            wr_planes(Vh, Vl, 0, 0, col, row0, x, false);
        }
    }
    __syncthreads();

    // ---- R4: X = A*V' + A4*(B2/720 + B4/40320) + (I + B2/2 + B4/24) ----
    {
        short8 vfh[2], vfl[2], uhi[2], a4f[2][2];
        float e2[2][4], e4[2][4];
#pragma unroll
        for (int c=0;c<2;++c){
            vfh[c] = ldp(Vh, col, 32*c+8*q);
            vfl[c] = ldp(Vl, col, 32*c+8*q);
            uhi[c] = poly_frag(P2h, P4h, col, 32*c+8*q, s2/720.f, 1.f/40320.f);
        }
#pragma unroll
        for (int i=0;i<2;++i)
#pragma unroll
            for (int c=0;c<2;++c) a4f[i][c] = ldp(P4h, Rw+16*i+m, 32*c+8*q);
#pragma unroll
        for (int i=0;i<2;++i){
            pair4(P2h, P2l, col, Rw+16*i+4*q, e2[i]);
            pair4(P4h, P4l, col, Rw+16*i+4*q, e4[i]);
        }
        __syncthreads();   // all reads of P2/P4/V done before X overwrites them

#pragma unroll
        for (int i=0;i<2;++i) acc[i] = (v4f){0.f,0.f,0.f,0.f};
#pragma unroll
        for (int c=0;c<2;++c)
#pragma unroll
            for (int i=0;i<2;++i){
                acc[i] = MFMA(a4f[i][c], uhi[c], acc[i]);
                acc[i] = MFMA(Ah[i][c], vfh[c], acc[i]);
                acc[i] = MFMA(Al[i][c], vfh[c], acc[i]);
                acc[i] = MFMA(Ah[i][c], vfl[c], acc[i]);
            }
#pragma unroll
        for (int i=0;i<2;++i){
            const int row0 = Rw+16*i+4*q;
            float x[4];
#pragma unroll
            for (int r=0;r<4;++r)
                x[r] = acc[i][r] + e2[i][r]*(s2*0.5f) + e4[i][r]*(1.f/24.f)
                     + ((row0+r)==col ? 1.f : 0.f);
            if (kq == 0){
                float* po = out + (size_t)blockIdx.x * 4096;
#pragma unroll
                for (int r=0;r<4;++r) po[(unsigned)(row0+r)*64 + col] = x[r];
            } else {
                wr_planes(Xch, Xcl, Xrh, Xrl, col, row0, x, true);
            }
        }
    }
    __syncthreads();

    // ---- k squarings: X = X*X (X not symmetric: row planes A-op, col planes B-op) ----
#pragma unroll 1
    for (int s = 0; s < kq; ++s){
        short8 xh[2][2], xl[2][2], bh[2], bl[2];
#pragma unroll
        for (int i=0;i<2;++i)
#pragma unroll
            for (int c=0;c<2;++c){
                xh[i][c] = ldp(Xrh, Rw+16*i+m, 32*c+8*q);
                xl[i][c] = ldp(Xrl, Rw+16*i+m, 32*c+8*q);
            }
#pragma unroll
        for (int c=0;c<2;++c){ bh[c]=ldp(Xch,col,32*c+8*q); bl[c]=ldp(Xcl,col,32*c+8*q); }
        __syncthreads();

#pragma unroll
        for (int i=0;i<2;++i) acc[i] = (v4f){0.f,0.f,0.f,0.f};
#pragma unroll
        for (int c=0;c<2;++c)
#pragma unroll
            for (int i=0;i<2;++i){
                acc[i] = MFMA(xh[i][c], bh[c], acc[i]);
                acc[i] = MFMA(xl[i][c], bh[c], acc[i]);
                acc[i] = MFMA(xh[i][c], bl[c], acc[i]);
            }

        if (s == kq-1){
            float* po = out + (size_t)blockIdx.x * 4096;
#pragma unroll
            for (int i=0;i<2;++i){
                const int row0 = Rw+16*i+4*q;
#pragma unroll
                for (int r=0;r<4;++r) po[(unsigned)(row0+r)*64 + col] = acc[i][r];
            }
        } else {
#pragma unroll
            for (int i=0;i<2;++i){
                float x[4] = {acc[i][0], acc[i][1], acc[i][2], acc[i][3]};
                wr_planes(Xch, Xcl, Xrh, Xrl, col, Rw+16*i+4*q, x, true);
            }
            __syncthreads();
        }
    }
}

extern "C" void kernel_launch(void* const* d_in, const int* in_sizes, int n_in,
                              void* d_out, int out_size, void* d_ws, size_t ws_size,
                              hipStream_t stream) {
    const float* vin = (const float*)d_in[0];
    float* out = (float*)d_out;
    const int batch = in_sizes[0] / NVEC;   // 4096
    hipLaunchKernelGGL(SkewSymMatrixExp_kernel, dim3(batch), dim3(NT), 0, stream,
                       vin, out);
}

// Round 5
// 166.476 us; speedup vs baseline: 3.0114x; 1.1584x over previous
//
#include <hip/hip_runtime.h>
#include <math.h>

#define NVEC 2016
#define NT   256
#define KMAX 8

typedef __attribute__((ext_vector_type(8))) short short8;
typedef __attribute__((ext_vector_type(4))) float v4f;

#define MFMA(a,b,c) __builtin_amdgcn_mfma_f32_16x16x32_bf16((a),(b),(c),0,0,0)

// RNE f32->bf16, result in low 16 bits
static __device__ __forceinline__ unsigned rne16(unsigned u){ return (u + 0x7FFFu + ((u>>16)&1u)) >> 16; }

// x -> h = trunc-bf16 (low16), l = rne-bf16 of exact residual. pair rel err ~2^-24.
static __device__ __forceinline__ void split_hl(float x, unsigned &h, unsigned &l){
    unsigned u = __float_as_uint(x);
    h = u >> 16;
    float r = x - __uint_as_float(u & 0xFFFF0000u);
    l = rne16(__float_as_uint(r));
}

// XOR-swizzled plane: 64 majors x 64 shorts (128B row = 8 x 16B granules).
// phys granule = g ^ (maj&7): col accesses spread across all banks.
static __device__ __forceinline__ int swz(int maj, int g){ return maj*64 + ((g ^ (maj & 7)) << 3); }
static __device__ __forceinline__ int swe(int maj, int t){ return swz(maj, t >> 3) + (t & 7); }

static __device__ __forceinline__ short8 ldp(const unsigned short* P, int maj, int off){
    return *(const short8*)&P[swz(maj, off >> 3)];
}

static __device__ __forceinline__ short8 neg8(short8 a){
    union { unsigned u[4]; short8 s; } X; X.s = a;
    X.u[0]^=0x80008000u; X.u[1]^=0x80008000u; X.u[2]^=0x80008000u; X.u[3]^=0x80008000u;
    return X.s;
}

// bf16 frag of (ca*P2 + cb*P4) read k-contig at (cc, off)
static __device__ __forceinline__ short8 polyf(const unsigned short* P2, const unsigned short* P4,
                                               int cc, int off, float ca, float cb){
    short8 a2 = ldp(P2, cc, off);
    short8 a4 = ldp(P4, cc, off);
    union { unsigned short u[8]; short8 s; } R;
#pragma unroll
    for (int e=0;e<8;++e){
        float fa = __uint_as_float(((unsigned)(unsigned short)a2[e])<<16);
        float fb = __uint_as_float(((unsigned)(unsigned short)a4[e])<<16);
        R.u[e] = (unsigned short)rne16(__float_as_uint(ca*fa + cb*fb));
    }
    return R.s;
}

// 4 consecutive rows of column cc as f32 (h+l planes)
static __device__ __forceinline__ void pair4(const unsigned short* Ph, const unsigned short* Pl,
                                             int cc, int row0, float o[4]){
    const int base = swe(cc, row0);
    uint2 h = *(const uint2*)&Ph[base];
    uint2 l = *(const uint2*)&Pl[base];
    o[0] = __uint_as_float(h.x<<16)           + __uint_as_float(l.x<<16);
    o[1] = __uint_as_float(h.x & 0xFFFF0000u) + __uint_as_float(l.x & 0xFFFF0000u);
    o[2] = __uint_as_float(h.y<<16)           + __uint_as_float(l.y<<16);
    o[3] = __uint_as_float(h.y & 0xFFFF0000u) + __uint_as_float(l.y & 0xFFFF0000u);
}

static __device__ __forceinline__ void pair4h(const unsigned short* Ph, int cc, int row0, float o[4]){
    const uint2 h = *(const uint2*)&Ph[swe(cc, row0)];
    o[0] = __uint_as_float(h.x<<16);
    o[1] = __uint_as_float(h.x & 0xFFFF0000u);
    o[2] = __uint_as_float(h.y<<16);
    o[3] = __uint_as_float(h.y & 0xFFFF0000u);
}

__global__ void __launch_bounds__(NT, 4)
SkewSymMatrixExp_kernel(const float* __restrict__ vin, float* __restrict__ out)
{
    // 5 planes x 8192 B = 40960 B exactly -> 4 blocks/CU
    __shared__ __attribute__((aligned(16))) unsigned short PAh[4096]; // A col -> V col -> Xc h
    __shared__ __attribute__((aligned(16))) unsigned short PAl[4096]; // A col -> V col -> Xc l
    __shared__ __attribute__((aligned(16))) unsigned short P2h[4096]; // A2 col -> Xr h
    __shared__ __attribute__((aligned(16))) unsigned short P2l[4096]; // A2 col -> Xr l
    __shared__ __attribute__((aligned(16))) unsigned short P4h[4096]; // scratch -> A4 (RNE h-only)

    const int tid  = threadIdx.x;
    const int wave = tid >> 6;
    const int lane = tid & 63;
    const int q    = lane >> 4;
    const int m    = lane & 15;
    const int Rw   = (wave >> 1) * 32;   // 32-row band
    const int Cw   = (wave & 1) * 32;    // 32-col band
    const float* v = vin + (size_t)blockIdx.x * NVEC;

    // ---- zero A planes ----
    {
        const uint4 z4 = make_uint4(0u,0u,0u,0u);
        for (int i = tid; i < 512; i += NT){ ((uint4*)PAh)[i] = z4; ((uint4*)PAl)[i] = z4; }
    }
    __syncthreads();

    // ---- scatter skew-symmetric A (unscaled) into col planes: P[c][r] = A[r][c] ----
    for (int p = tid; p < NVEC; p += NT) {
        int i = (int)((127.0f - sqrtf(16129.0f - 8.0f * (float)p)) * 0.5f);
        if (i < 0) i = 0;
        if (i > 62) i = 62;
        while (i > 0 && (63*i - ((i*(i-1))>>1)) > p) --i;
        while (i < 62 && (63*(i+1) - (((i+1)*i)>>1)) <= p) ++i;
        const int off = 63*i - ((i*(i-1))>>1);
        const int j = i + 1 + (p - off);
        unsigned h, l; split_hl(v[p], h, l);
        PAh[swe(j, i)] = (unsigned short)(h ^ 0x8000u);   // A[i][j] = -v
        PAl[swe(j, i)] = (unsigned short)(l ^ 0x8000u);
        PAh[swe(i, j)] = (unsigned short)h;               // A[j][i] = +v
        PAl[swe(i, j)] = (unsigned short)l;
    }
    __syncthreads();

    // ---- cache A-op fragments in registers (live through R4) ----
    short8 Ah[2][2], Al[2][2];
#pragma unroll
    for (int i=0;i<2;++i)
#pragma unroll
        for (int c=0;c<2;++c){
            Ah[i][c] = neg8(ldp(PAh, Rw+16*i+m, 32*c+8*q));   // A[r][k] = -P[r][k]
            Al[i][c] = neg8(ldp(PAl, Rw+16*i+m, 32*c+8*q));
        }

    v4f acc[2][2];

    // ---- R1: A2 = A*A (unscaled) -> P2 h/l ----
#pragma unroll
    for (int i=0;i<2;++i)
#pragma unroll
        for (int j=0;j<2;++j) acc[i][j] = (v4f){0.f,0.f,0.f,0.f};
#pragma unroll
    for (int c=0;c<2;++c)
#pragma unroll
        for (int j=0;j<2;++j){
            short8 bh = ldp(PAh, Cw+16*j+m, 32*c+8*q);
            short8 bl = ldp(PAl, Cw+16*j+m, 32*c+8*q);
#pragma unroll
            for (int i=0;i<2;++i){
                acc[i][j] = MFMA(Ah[i][c], bh, acc[i][j]);
                acc[i][j] = MFMA(Al[i][c], bh, acc[i][j]);
                acc[i][j] = MFMA(Ah[i][c], bl, acc[i][j]);
            }
        }
#pragma unroll
    for (int i=0;i<2;++i)
#pragma unroll
        for (int j=0;j<2;++j){
            const int row0 = Rw+16*i+4*q, cc = Cw+16*j+m;
            unsigned h[4], l[4];
#pragma unroll
            for (int r=0;r<4;++r) split_hl(acc[i][j][r], h[r], l[r]);
            const int base = swe(cc, row0);
            *(uint2*)&P2h[base] = make_uint2(h[0]|(h[1]<<16), h[2]|(h[3]<<16));
            *(uint2*)&P2l[base] = make_uint2(l[0]|(l[1]<<16), l[2]|(l[3]<<16));
        }
    __syncthreads();

    // ---- k from ||A2||_1 (scratch aliases P4h; every wave reduces redundantly) ----
    float* scratch = (float*)P4h;
    {
        const int c0 = tid & 63, seg = tid >> 6;
        float s = 0.f;
#pragma unroll
        for (int gg=0; gg<2; ++gg){
            const uint4 w = *(const uint4*)&P2h[swz(c0, 2*seg+gg)];
            const unsigned ws[4] = {w.x, w.y, w.z, w.w};
#pragma unroll
            for (int e=0;e<4;++e){
                s += __uint_as_float((ws[e] & 0x7FFFu) << 16);
                s += __uint_as_float(ws[e] & 0x7FFF0000u);
            }
        }
        scratch[tid] = s;
    }
    __syncthreads();
    int kq; float s1, s2, s4;
    {
        float s = scratch[lane] + scratch[lane+64] + scratch[lane+128] + scratch[lane+192];
#pragma unroll
        for (int o=1;o<64;o<<=1) s = fmaxf(s, __shfl_xor(s, o, 64));
        float est = sqrtf(s) * 0.625f;          // sqrt(||A2||_1)/theta, theta=1.6
        kq = 0;
        if (est > 1.f) kq = (int)ceilf(log2f(est));
        if (kq > KMAX) kq = KMAX;
        s1 = exp2f(-(float)kq);                 // B = s1*A
        s2 = s1*s1; s4 = s2*s2;
    }
    __syncthreads();                            // all scratch reads done before P4h writes

    // ---- R2: A4 = s4 * A2*A2 (RNE bf16, h-only) -> P4h ----
#pragma unroll
    for (int i=0;i<2;++i)
#pragma unroll
        for (int j=0;j<2;++j) acc[i][j] = (v4f){0.f,0.f,0.f,0.f};
#pragma unroll
    for (int c=0;c<2;++c){
        short8 a2h[2], a2l[2];
#pragma unroll
        for (int i=0;i<2;++i){
            a2h[i] = ldp(P2h, Rw+16*i+m, 32*c+8*q);
            a2l[i] = ldp(P2l, Rw+16*i+m, 32*c+8*q);
        }
#pragma unroll
        for (int j=0;j<2;++j){
            short8 bh = ldp(P2h, Cw+16*j+m, 32*c+8*q);
            short8 bl = ldp(P2l, Cw+16*j+m, 32*c+8*q);
#pragma unroll
            for (int i=0;i<2;++i){
                acc[i][j] = MFMA(a2h[i], bh, acc[i][j]);
                acc[i][j] = MFMA(a2l[i], bh, acc[i][j]);
                acc[i][j] = MFMA(a2h[i], bl, acc[i][j]);
            }
        }
    }
#pragma unroll
    for (int i=0;i<2;++i)
#pragma unroll
        for (int j=0;j<2;++j){
            const int row0 = Rw+16*i+4*q, cc = Cw+16*j+m;
            unsigned h[4];
#pragma unroll
            for (int r=0;r<4;++r) h[r] = rne16(__float_as_uint(s4*acc[i][j][r]));
            *(uint2*)&P4h[swe(cc,row0)] = make_uint2(h[0]|(h[1]<<16), h[2]|(h[3]<<16));
        }
    __syncthreads();

    // ---- R3: V = s1*( I + B2/6 + B4/120 + B4*(B2/5040 + B4/362880) ) -> PA planes ----
#pragma unroll
    for (int i=0;i<2;++i)
#pragma unroll
        for (int j=0;j<2;++j) acc[i][j] = (v4f){0.f,0.f,0.f,0.f};
#pragma unroll
    for (int c=0;c<2;++c){
        short8 a4f[2];
#pragma unroll
        for (int i=0;i<2;++i) a4f[i] = ldp(P4h, Rw+16*i+m, 32*c+8*q);
#pragma unroll
        for (int j=0;j<2;++j){
            short8 vh = polyf(P2h, P4h, Cw+16*j+m, 32*c+8*q, s2/5040.f, 1.f/362880.f);
#pragma unroll
            for (int i=0;i<2;++i) acc[i][j] = MFMA(a4f[i], vh, acc[i][j]);
        }
    }
#pragma unroll
    for (int i=0;i<2;++i)
#pragma unroll
        for (int j=0;j<2;++j){
            const int row0 = Rw+16*i+4*q, cc = Cw+16*j+m;
            float e2[4], e4[4];
            pair4(P2h, P2l, cc, row0, e2);
            pair4h(P4h, cc, row0, e4);
            unsigned h[4], l[4];
#pragma unroll
            for (int r=0;r<4;++r){
                float x = s1*( acc[i][j][r] + e2[r]*(s2/6.f) + e4[r]*(1.f/120.f)
                               + ((row0+r)==cc ? 1.f : 0.f) );
                split_hl(x, h[r], l[r]);
            }
            const int base = swe(cc, row0);
            *(uint2*)&PAh[base] = make_uint2(h[0]|(h[1]<<16), h[2]|(h[3]<<16));
            *(uint2*)&PAl[base] = make_uint2(l[0]|(l[1]<<16), l[2]|(l[3]<<16));
        }
    __syncthreads();

    // ---- R4: X = A*V + B4*(B2/720 + B4/40320) + (I + B2/2 + B4/24) ----
#pragma unroll
    for (int i=0;i<2;++i)
#pragma unroll
        for (int j=0;j<2;++j) acc[i][j] = (v4f){0.f,0.f,0.f,0.f};
    // pass 1: B4 * uhi
#pragma unroll
    for (int c=0;c<2;++c){
        short8 a4f[2];
#pragma unroll
        for (int i=0;i<2;++i) a4f[i] = ldp(P4h, Rw+16*i+m, 32*c+8*q);
#pragma unroll
        for (int j=0;j<2;++j){
            short8 uh = polyf(P2h, P4h, Cw+16*j+m, 32*c+8*q, s2/720.f, 1.f/40320.f);
#pragma unroll
            for (int i=0;i<2;++i) acc[i][j] = MFMA(a4f[i], uh, acc[i][j]);
        }
    }
    // pass 2: A * V (A from registers; A-regs die here)
#pragma unroll
    for (int c=0;c<2;++c)
#pragma unroll
        for (int j=0;j<2;++j){
            short8 vfh = ldp(PAh, Cw+16*j+m, 32*c+8*q);
            short8 vfl = ldp(PAl, Cw+16*j+m, 32*c+8*q);
#pragma unroll
            for (int i=0;i<2;++i){
                acc[i][j] = MFMA(Ah[i][c], vfh, acc[i][j]);
                acc[i][j] = MFMA(Al[i][c], vfh, acc[i][j]);
                acc[i][j] = MFMA(Ah[i][c], vfl, acc[i][j]);
            }
        }
    {
        float e2[2][2][4], e4[2][2][4];
#pragma unroll
        for (int i=0;i<2;++i)
#pragma unroll
            for (int j=0;j<2;++j){
                pair4(P2h, P2l, Cw+16*j+m, Rw+16*i+4*q, e2[i][j]);
                pair4h(P4h, Cw+16*j+m, Rw+16*i+4*q, e4[i][j]);
            }
        __syncthreads();   // all reads of P2/P4/V done before X overwrites

#pragma unroll
        for (int i=0;i<2;++i)
#pragma unroll
            for (int j=0;j<2;++j){
                const int row0 = Rw+16*i+4*q, cc = Cw+16*j+m;
                float x[4];
#pragma unroll
                for (int r=0;r<4;++r)
                    x[r] = acc[i][j][r] + e2[i][j][r]*(s2*0.5f) + e4[i][j][r]*(1.f/24.f)
                         + ((row0+r)==cc ? 1.f : 0.f);
                if (kq == 0){
                    float* po = out + (size_t)blockIdx.x * 4096;
#pragma unroll
                    for (int r=0;r<4;++r) po[(unsigned)(row0+r)*64 + cc] = x[r];
                } else {
                    unsigned h[4], l[4];
#pragma unroll
                    for (int r=0;r<4;++r) split_hl(x[r], h[r], l[r]);
                    const int base = swe(cc, row0);
                    *(uint2*)&PAh[base] = make_uint2(h[0]|(h[1]<<16), h[2]|(h[3]<<16));  // Xc
                    *(uint2*)&PAl[base] = make_uint2(l[0]|(l[1]<<16), l[2]|(l[3]<<16));
#pragma unroll
                    for (int r=0;r<4;++r){                                               // Xr
                        P2h[swe(row0+r, cc)] = (unsigned short)h[r];
                        P2l[swe(row0+r, cc)] = (unsigned short)l[r];
                    }
                }
            }
    }
    __syncthreads();

    // ---- kq squarings: X = X*X (Xr=P2 planes A-op, Xc=PA planes B-op) ----
#pragma unroll 1
    for (int s = 0; s < kq; ++s){
#pragma unroll
        for (int i=0;i<2;++i)
#pragma unroll
            for (int j=0;j<2;++j) acc[i][j] = (v4f){0.f,0.f,0.f,0.f};
#pragma unroll
        for (int c=0;c<2;++c){
            short8 xh[2], xl[2];
#pragma unroll
            for (int i=0;i<2;++i){
                xh[i] = ldp(P2h, Rw+16*i+m, 32*c+8*q);
                xl[i] = ldp(P2l, Rw+16*i+m, 32*c+8*q);
            }
#pragma unroll
            for (int j=0;j<2;++j){
                short8 bh = ldp(PAh, Cw+16*j+m, 32*c+8*q);
                short8 bl = ldp(PAl, Cw+16*j+m, 32*c+8*q);
#pragma unroll
                for (int i=0;i<2;++i){
                    acc[i][j] = MFMA(xh[i], bh, acc[i][j]);
                    acc[i][j] = MFMA(xl[i], bh, acc[i][j]);
                    acc[i][j] = MFMA(xh[i], bl, acc[i][j]);
                }
            }
        }
        __syncthreads();   // all reads done before overwrite

        if (s == kq-1){
            float* po = out + (size_t)blockIdx.x * 4096;
#pragma unroll
            for (int i=0;i<2;++i)
#pragma unroll
                for (int j=0;j<2;++j){
                    const int row0 = Rw+16*i+4*q, cc = Cw+16*j+m;
#pragma unroll
                    for (int r=0;r<4;++r) po[(unsigned)(row0+r)*64 + cc] = acc[i][j][r];
                }
        } else {
#pragma unroll
            for (int i=0;i<2;++i)
#pragma unroll
                for (int j=0;j<2;++j){
                    const int row0 = Rw+16*i+4*q, cc = Cw+16*j+m;
                    unsigned h[4], l[4];
#pragma unroll
                    for (int r=0;r<4;++r) split_hl(acc[i][j][r], h[r], l[r]);
                    const int base = swe(cc, row0);
                    *(uint2*)&PAh[base] = make_uint2(h[0]|(h[1]<<16), h[2]|(h[3]<<16));
                    *(uint2*)&PAl[base] = make_uint2(l[0]|(l[1]<<16), l[2]|(l[3]<<16));
#pragma unroll
                    for (int r=0;r<4;++r){
                        P2h[swe(row0+r, cc)] = (unsigned short)h[r];
                        P2l[swe(row0+r, cc)] = (unsigned short)l[r];
                    }
                }
            __syncthreads();
        }
    }
}

extern "C" void kernel_launch(void* const* d_in, const int* in_sizes, int n_in,
                              void* d_out, int out_size, void* d_ws, size_t ws_size,
                              hipStream_t stream) {
    const float* vin = (const float*)d_in[0];
    float* out = (float*)d_out;
    const int batch = in_sizes[0] / NVEC;   // 4096
    hipLaunchKernelGGL(SkewSymMatrixExp_kernel, dim3(batch), dim3(NT), 0, stream,
                       vin, out);
}